// Round 4
// baseline (345.243 us; speedup 1.0000x reference)
//
#include <hip/hip_runtime.h>

#define DIM 768
#define NHEADS 12
#define HDIM 64
#define BATCH 8
#define LQ 1024
#define LKV 1024
#define ATTN_SCALE 0.125f

typedef __bf16 bf16;
typedef __bf16 bf16x4 __attribute__((ext_vector_type(4)));
typedef __bf16 bf16x8 __attribute__((ext_vector_type(8)));
typedef short s16x4 __attribute__((ext_vector_type(4)));
typedef float f32x4 __attribute__((ext_vector_type(4)));

union B4 { bf16x4 h; s16x4 s; };

static __device__ __forceinline__ f32x4 mfma_k32(bf16x8 a, bf16x8 b, f32x4 c) {
    return __builtin_amdgcn_mfma_f32_16x16x32_bf16(a, b, c, 0, 0, 0);
}
static __device__ __forceinline__ f32x4 mfma_k16(s16x4 a, s16x4 b, f32x4 c) {
    return __builtin_amdgcn_mfma_f32_16x16x16bf16_1k(a, b, c, 0, 0, 0);
}

// ---------------- fp32 -> bf16 converts (fused multi-tensor) ----------------
__global__ void cvt_qkv(const float4* __restrict__ q, const float4* __restrict__ kv,
                        bf16x4* __restrict__ qb, bf16x4* __restrict__ kvb, int n4) {
    int i = blockIdx.x * 256 + threadIdx.x;
    if (i >= n4) return;
    const float4* src = blockIdx.y ? kv : q;
    bf16x4* dst = blockIdx.y ? kvb : qb;
    float4 v = src[i];
    bf16x4 o;
    o[0] = (bf16)v.x; o[1] = (bf16)v.y; o[2] = (bf16)v.z; o[3] = (bf16)v.w;
    dst[i] = o;
}

__global__ void cvt_w(const float4* __restrict__ Wq, const float4* __restrict__ Wkv,
                      const float4* __restrict__ Wp,
                      bf16x4* __restrict__ wqb, bf16x4* __restrict__ wkvb,
                      bf16x4* __restrict__ wpb, int n4) {
    int i = blockIdx.x * 256 + threadIdx.x;
    if (i >= n4) return;
    int y = blockIdx.y;
    const float4* src; bf16x4* dst;
    if (y == 0)      { src = Wq;        dst = wqb; }
    else if (y == 3) { src = Wp;        dst = wpb; }
    else             { src = Wkv + (y - 1) * n4; dst = wkvb + (y - 1) * n4; }
    float4 v = src[i];
    bf16x4 o;
    o[0] = (bf16)v.x; o[1] = (bf16)v.y; o[2] = (bf16)v.z; o[3] = (bf16)v.w;
    dst[i] = o;
}

// ---------------- GEMM: C[M,N] = A[M,K] @ B[N,K]^T ----------------
// 128x128 tile, BK=32, synchronous uint4 staging into padded LDS (stride 40).
// MODE 0: bf16 out, row-major stride N (swapped-operand epilogue, 8B packed)
// MODE 1: fp32 out + bias, row-major stride N (swapped, float4 stores)
// MODE 2: V-projection: out written transposed to Vt (B,H,64,LKV), non-swapped
template<int MODE>
__global__ __launch_bounds__(256) void gemm_bt(
    const bf16* __restrict__ A, const bf16* __restrict__ B,
    void* __restrict__ Cp, const float* __restrict__ bias,
    int M, int N, int K)
{
    __shared__ bf16 As[128 * 40];
    __shared__ bf16 Bs[128 * 40];
    const int tid  = threadIdx.x;
    const int lane = tid & 63;
    const int w    = tid >> 6;
    const int wm = (w >> 1) * 64;
    const int wn = (w & 1) * 64;
    const int m0 = blockIdx.x * 128;
    const int n0 = blockIdx.y * 128;
    const int lq = lane & 15;
    const int quad = lane >> 4;
    const int row_l = tid >> 1;          // 0..127
    const int col_l = (tid & 1) * 16;    // 0 or 16

    f32x4 acc[4][4] = {};

    for (int k0 = 0; k0 < K; k0 += 32) {
        const bf16* ga = A + (size_t)(m0 + row_l) * K + k0 + col_l;
        const bf16* gb = B + (size_t)(n0 + row_l) * K + k0 + col_l;
        *(uint4*)&As[row_l * 40 + col_l]     = *(const uint4*)(ga);
        *(uint4*)&As[row_l * 40 + col_l + 8] = *(const uint4*)(ga + 8);
        *(uint4*)&Bs[row_l * 40 + col_l]     = *(const uint4*)(gb);
        *(uint4*)&Bs[row_l * 40 + col_l + 8] = *(const uint4*)(gb + 8);
        __syncthreads();

        bf16x8 a[4], b[4];
        #pragma unroll
        for (int i = 0; i < 4; i++)
            a[i] = *(const bf16x8*)&As[(wm + i * 16 + lq) * 40 + quad * 8];
        #pragma unroll
        for (int j = 0; j < 4; j++)
            b[j] = *(const bf16x8*)&Bs[(wn + j * 16 + lq) * 40 + quad * 8];
        #pragma unroll
        for (int i = 0; i < 4; i++)
            #pragma unroll
            for (int j = 0; j < 4; j++)
                acc[i][j] = (MODE == 2) ? mfma_k32(a[i], b[j], acc[i][j])
                                        : mfma_k32(b[j], a[i], acc[i][j]);
        __syncthreads();
    }

    if (MODE == 2) {
        // acc[i][j]: rows = kv (m0+wm+i*16+quad*4+r), cols = d (n0+wn+j*16+lq)
        bf16* Vt = (bf16*)Cp;
        #pragma unroll
        for (int i = 0; i < 4; i++) {
            const int base_m = m0 + wm + i * 16;
            const int b_idx = base_m >> 10;
            const int kvl = (base_m & 1023) + quad * 4;
            #pragma unroll
            for (int j = 0; j < 4; j++) {
                const int nl = wn + j * 16 + lq;
                const int h = (n0 + nl) >> 6;
                const int d = (n0 + nl) & 63;
                B4 pk;
                #pragma unroll
                for (int r = 0; r < 4; r++) pk.h[r] = (bf16)acc[i][j][r];
                *(s16x4*)&Vt[(((size_t)b_idx * NHEADS + h) * HDIM + d) * LKV + kvl] = pk.s;
            }
        }
    } else {
        // swapped: lane holds row m = m0+wm+i*16+lq, 4 consecutive cols
        #pragma unroll
        for (int i = 0; i < 4; i++) {
            const size_t row = m0 + wm + i * 16 + lq;
            #pragma unroll
            for (int j = 0; j < 4; j++) {
                const int col = n0 + wn + j * 16 + quad * 4;
                if (MODE == 1) {
                    float4 bj = *(const float4*)&bias[col];
                    float4 o;
                    o.x = acc[i][j][0] + bj.x; o.y = acc[i][j][1] + bj.y;
                    o.z = acc[i][j][2] + bj.z; o.w = acc[i][j][3] + bj.w;
                    *(float4*)&((float*)Cp)[row * N + col] = o;
                } else {
                    B4 pk;
                    #pragma unroll
                    for (int r = 0; r < 4; r++) pk.h[r] = (bf16)acc[i][j][r];
                    *(s16x4*)&((bf16*)Cp)[row * N + col] = pk.s;
                }
            }
        }
    }
}

// ---------------- fused attention (transposed-S, 128-q blocks, 2 strips/wave) ----------------
__global__ __launch_bounds__(256) void attn_kernel(
    const bf16* __restrict__ Qb,   // (B*LQ, 768)
    const bf16* __restrict__ Kb,   // (B*LKV, 768)
    const bf16* __restrict__ Vt,   // (B*H*64, LKV)
    const float* __restrict__ pos, // (H, LQ, LKV)
    bf16* __restrict__ O)          // (B*LQ, 768)
{
    __shared__ bf16 Qs[128 * 72];
    __shared__ bf16 Ks[64 * 72];   // [kv][d]
    __shared__ bf16 Vs[64 * 72];   // [d][kv]

    const int by = blockIdx.y;     // h-major for pos L2 locality
    const int h = by >> 3, b = by & 7;
    const int bh = b * NHEADS + h;
    const int q0 = blockIdx.x * 128;
    const int t = threadIdx.x;
    const int lane = t & 63;
    const int w = t >> 6;
    const int lq = lane & 15;
    const int quad = lane >> 4;

    #pragma unroll
    for (int p = 0; p < 4; p++) {
        int row = (t >> 3) + p * 32;
        int c8  = (t & 7) * 8;
        *(uint4*)&Qs[row * 72 + c8] =
            *(const uint4*)(Qb + (size_t)(b * LQ + q0 + row) * DIM + h * HDIM + c8);
    }
    __syncthreads();
    bf16x8 qa[2][2];
    #pragma unroll
    for (int s = 0; s < 2; s++) {
        qa[s][0] = *(const bf16x8*)&Qs[(s * 64 + w * 16 + lq) * 72 +      quad * 8];
        qa[s][1] = *(const bf16x8*)&Qs[(s * 64 + w * 16 + lq) * 72 + 32 + quad * 8];
    }

    float m_r[2] = {-1e30f, -1e30f}, l_r[2] = {0.f, 0.f};
    f32x4 o_acc[2][4] = {};

    const float4* pos4[2];
    #pragma unroll
    for (int s = 0; s < 2; s++)
        pos4[s] = (const float4*)(pos + ((size_t)h * LQ + q0 + s * 64 + w * 16 + lq) * LKV);

    for (int kv0 = 0; kv0 < LKV; kv0 += 64) {
        #pragma unroll
        for (int p = 0; p < 2; p++) {
            int row = (t >> 3) + p * 32;
            int c8  = (t & 7) * 8;
            *(uint4*)&Ks[row * 72 + c8] =
                *(const uint4*)(Kb + (size_t)(b * LKV + kv0 + row) * DIM + h * HDIM + c8);
            *(uint4*)&Vs[row * 72 + c8] =
                *(const uint4*)(Vt + (size_t)(bh * HDIM + row) * LKV + kv0 + c8);
        }
        __syncthreads();

        #pragma unroll
        for (int s = 0; s < 2; s++) {
            float4 pb[4];
            #pragma unroll
            for (int kvblk = 0; kvblk < 4; kvblk++)
                pb[kvblk] = pos4[s][(kv0 >> 2) + kvblk * 4 + quad];

            f32x4 sc[4];
            #pragma unroll
            for (int kvblk = 0; kvblk < 4; kvblk++) {
                sc[kvblk] = (f32x4){0.f, 0.f, 0.f, 0.f};
                #pragma unroll
                for (int kt = 0; kt < 2; kt++) {
                    bf16x8 ak = *(const bf16x8*)&Ks[(kvblk * 16 + lq) * 72 + kt * 32 + quad * 8];
                    sc[kvblk] = mfma_k32(ak, qa[s][kt], sc[kvblk]);
                }
            }

            float sv[4][4];
            #pragma unroll
            for (int kvblk = 0; kvblk < 4; kvblk++) {
                sv[kvblk][0] = sc[kvblk][0] * ATTN_SCALE + pb[kvblk].x;
                sv[kvblk][1] = sc[kvblk][1] * ATTN_SCALE + pb[kvblk].y;
                sv[kvblk][2] = sc[kvblk][2] * ATTN_SCALE + pb[kvblk].z;
                sv[kvblk][3] = sc[kvblk][3] * ATTN_SCALE + pb[kvblk].w;
            }

            float tmax = sv[0][0];
            #pragma unroll
            for (int kvblk = 0; kvblk < 4; kvblk++)
                #pragma unroll
                for (int r = 0; r < 4; r++)
                    tmax = fmaxf(tmax, sv[kvblk][r]);
            tmax = fmaxf(tmax, __shfl_xor(tmax, 16));
            tmax = fmaxf(tmax, __shfl_xor(tmax, 32));
            float mn = fmaxf(m_r[s], tmax);
            float alpha = __expf(m_r[s] - mn);
            float rs = 0.f;
            B4 pfrag[4];
            #pragma unroll
            for (int kvblk = 0; kvblk < 4; kvblk++) {
                #pragma unroll
                for (int r = 0; r < 4; r++) {
                    float pv = __expf(sv[kvblk][r] - mn);
                    rs += pv;
                    pfrag[kvblk].h[r] = (bf16)pv;
                }
            }
            rs += __shfl_xor(rs, 16);
            rs += __shfl_xor(rs, 32);
            l_r[s] = l_r[s] * alpha + rs;
            m_r[s] = mn;

            #pragma unroll
            for (int dblk = 0; dblk < 4; dblk++) {
                o_acc[s][dblk][0] *= alpha; o_acc[s][dblk][1] *= alpha;
                o_acc[s][dblk][2] *= alpha; o_acc[s][dblk][3] *= alpha;
            }

            #pragma unroll
            for (int dblk = 0; dblk < 4; dblk++) {
                #pragma unroll
                for (int kvblk = 0; kvblk < 4; kvblk++) {
                    s16x4 va = *(const s16x4*)&Vs[(dblk * 16 + lq) * 72 + kvblk * 16 + quad * 4];
                    o_acc[s][dblk] = mfma_k16(va, pfrag[kvblk].s, o_acc[s][dblk]);
                }
            }
        }
        __syncthreads();
    }

    #pragma unroll
    for (int s = 0; s < 2; s++) {
        float inv = 1.f / l_r[s];
        const size_t orow = (size_t)(b * LQ + q0 + s * 64 + w * 16 + lq) * DIM + h * HDIM;
        #pragma unroll
        for (int dblk = 0; dblk < 4; dblk++) {
            B4 ob;
            #pragma unroll
            for (int r = 0; r < 4; r++) ob.h[r] = (bf16)(o_acc[s][dblk][r] * inv);
            *(s16x4*)&O[orow + dblk * 16 + quad * 4] = ob.s;
        }
    }
}

// ---------------- host ----------------
extern "C" void kernel_launch(void* const* d_in, const int* in_sizes, int n_in,
                              void* d_out, int out_size, void* d_ws, size_t ws_size,
                              hipStream_t stream) {
    const float* q     = (const float*)d_in[0];
    const float* kv    = (const float*)d_in[1];
    const float* pos   = (const float*)d_in[2];
    const float* Wq    = (const float*)d_in[3];
    const float* Wkv   = (const float*)d_in[4];
    const float* Wproj = (const float*)d_in[5];
    const float* bproj = (const float*)d_in[6];
    float* out = (float*)d_out;

    char* ws = (char*)d_ws;
    size_t off = 0;
    auto alloc = [&](size_t bytes) -> void* {
        void* p = ws + off;
        off += (bytes + 255) & ~(size_t)255;
        return p;
    };

    const int M = BATCH * LQ;   // 8192
    bf16* qb   = (bf16*)alloc((size_t)M * DIM * 2);
    bf16* kvb  = (bf16*)alloc((size_t)M * DIM * 2);
    bf16* wqb  = (bf16*)alloc((size_t)DIM * DIM * 2);
    bf16* wkvb = (bf16*)alloc((size_t)2 * DIM * DIM * 2);
    bf16* wpb  = (bf16*)alloc((size_t)DIM * DIM * 2);
    bf16* Qp   = (bf16*)alloc((size_t)M * DIM * 2);
    bf16* Kp   = (bf16*)alloc((size_t)M * DIM * 2);
    bf16* Vt   = (bf16*)alloc((size_t)BATCH * NHEADS * HDIM * LKV * 2);
    bf16* Ob   = (bf16*)alloc((size_t)M * DIM * 2);

    {
        int n4 = M * DIM / 4;
        cvt_qkv<<<dim3((n4 + 255) / 256, 2), 256, 0, stream>>>(
            (const float4*)q, (const float4*)kv, (bf16x4*)qb, (bf16x4*)kvb, n4);
        int w4 = DIM * DIM / 4;
        cvt_w<<<dim3((w4 + 255) / 256, 4), 256, 0, stream>>>(
            (const float4*)Wq, (const float4*)Wkv, (const float4*)Wproj,
            (bf16x4*)wqb, (bf16x4*)wkvb, (bf16x4*)wpb, w4);
    }

    gemm_bt<0><<<dim3(M / 128, DIM / 128), 256, 0, stream>>>(qb, wqb, Qp, nullptr, M, DIM, DIM);
    gemm_bt<0><<<dim3(M / 128, DIM / 128), 256, 0, stream>>>(kvb, wkvb, Kp, nullptr, M, DIM, DIM);
    gemm_bt<2><<<dim3(M / 128, DIM / 128), 256, 0, stream>>>(kvb, wkvb + (size_t)DIM * DIM, Vt, nullptr, M, DIM, DIM);
    attn_kernel<<<dim3(LQ / 128, NHEADS * BATCH), 256, 0, stream>>>(Qp, Kp, Vt, pos, Ob);
    gemm_bt<1><<<dim3(M / 128, DIM / 128), 256, 0, stream>>>(Ob, wpb, out, bproj, M, DIM, DIM);
}

// Round 5
// 316.971 us; speedup vs baseline: 1.0892x; 1.0892x over previous
//
#include <hip/hip_runtime.h>

#define DIM 768
#define NHEADS 12
#define HDIM 64
#define BATCH 8
#define LQ 1024
#define LKV 1024
#define ATTN_SCALE 0.125f

typedef __bf16 bf16;
typedef __bf16 bf16x4 __attribute__((ext_vector_type(4)));
typedef __bf16 bf16x8 __attribute__((ext_vector_type(8)));
typedef short s16x4 __attribute__((ext_vector_type(4)));
typedef float f32x4 __attribute__((ext_vector_type(4)));

union B4 { bf16x4 h; s16x4 s; };

static __device__ __forceinline__ f32x4 mfma_k32(bf16x8 a, bf16x8 b, f32x4 c) {
    return __builtin_amdgcn_mfma_f32_16x16x32_bf16(a, b, c, 0, 0, 0);
}
static __device__ __forceinline__ f32x4 mfma_k16(s16x4 a, s16x4 b, f32x4 c) {
    return __builtin_amdgcn_mfma_f32_16x16x16bf16_1k(a, b, c, 0, 0, 0);
}

// ---------------- fp32 -> bf16 converts (fused multi-tensor) ----------------
__global__ void cvt_qkv(const float4* __restrict__ q, const float4* __restrict__ kv,
                        bf16x4* __restrict__ qb, bf16x4* __restrict__ kvb, int n4) {
    int i = blockIdx.x * 256 + threadIdx.x;
    if (i >= n4) return;
    const float4* src = blockIdx.y ? kv : q;
    bf16x4* dst = blockIdx.y ? kvb : qb;
    float4 v = src[i];
    bf16x4 o;
    o[0] = (bf16)v.x; o[1] = (bf16)v.y; o[2] = (bf16)v.z; o[3] = (bf16)v.w;
    dst[i] = o;
}

// wall = [Wq(768) ; Wkv(1536)] rows, plus Wproj separately. y in 0..3
__global__ void cvt_w(const float4* __restrict__ Wq, const float4* __restrict__ Wkv,
                      const float4* __restrict__ Wp,
                      bf16x4* __restrict__ wall, bf16x4* __restrict__ wpb, int n4) {
    int i = blockIdx.x * 256 + threadIdx.x;
    if (i >= n4) return;
    int y = blockIdx.y;
    const float4* src; bf16x4* dst;
    if (y == 0)      { src = Wq;             dst = wall; }
    else if (y == 3) { src = Wp;             dst = wpb; }
    else             { src = Wkv + (y - 1) * n4; dst = wall + y * n4; }
    float4 v = src[i];
    bf16x4 o;
    o[0] = (bf16)v.x; o[1] = (bf16)v.y; o[2] = (bf16)v.z; o[3] = (bf16)v.w;
    dst[i] = o;
}

// ---------------- fused projection GEMM ----------------
// C[8192, 2304] = [qb|kvb] @ [Wq;WkvK;WkvV]^T, column range picks A + epilogue:
//   n0 in [0,768):     Qp bf16 (swapped epilogue)
//   n0 in [768,1536):  Kp bf16 (swapped)
//   n0 in [1536,2304): Vt (B,H,64,LKV) transposed (non-swapped)
__global__ __launch_bounds__(256) void proj_gemm(
    const bf16* __restrict__ qb, const bf16* __restrict__ kvb,
    const bf16* __restrict__ W,   // 2304 x 768 bf16
    bf16* __restrict__ Qp, bf16* __restrict__ Kp, bf16* __restrict__ Vt)
{
    __shared__ bf16 As[128 * 40];
    __shared__ bf16 Bs[128 * 40];
    const int tid  = threadIdx.x;
    const int lane = tid & 63;
    const int w    = tid >> 6;
    const int wm = (w >> 1) * 64;
    const int wn = (w & 1) * 64;
    const int m0 = blockIdx.x * 128;
    const int n0 = blockIdx.y * 128;
    const int K = DIM;
    const int lq = lane & 15;
    const int quad = lane >> 4;
    const int row_l = tid >> 1;
    const int col_l = (tid & 1) * 16;

    const bf16* A = (n0 < DIM) ? qb : kvb;
    const int isV = (n0 >= 2 * DIM);

    f32x4 acc[4][4] = {};

    for (int k0 = 0; k0 < K; k0 += 32) {
        const bf16* ga = A + (size_t)(m0 + row_l) * K + k0 + col_l;
        const bf16* gb = W + (size_t)(n0 + row_l) * K + k0 + col_l;
        *(uint4*)&As[row_l * 40 + col_l]     = *(const uint4*)(ga);
        *(uint4*)&As[row_l * 40 + col_l + 8] = *(const uint4*)(ga + 8);
        *(uint4*)&Bs[row_l * 40 + col_l]     = *(const uint4*)(gb);
        *(uint4*)&Bs[row_l * 40 + col_l + 8] = *(const uint4*)(gb + 8);
        __syncthreads();

        bf16x8 a[4], b[4];
        #pragma unroll
        for (int i = 0; i < 4; i++)
            a[i] = *(const bf16x8*)&As[(wm + i * 16 + lq) * 40 + quad * 8];
        #pragma unroll
        for (int j = 0; j < 4; j++)
            b[j] = *(const bf16x8*)&Bs[(wn + j * 16 + lq) * 40 + quad * 8];
        if (isV) {
            #pragma unroll
            for (int i = 0; i < 4; i++)
                #pragma unroll
                for (int j = 0; j < 4; j++)
                    acc[i][j] = mfma_k32(a[i], b[j], acc[i][j]);
        } else {
            #pragma unroll
            for (int i = 0; i < 4; i++)
                #pragma unroll
                for (int j = 0; j < 4; j++)
                    acc[i][j] = mfma_k32(b[j], a[i], acc[i][j]);
        }
        __syncthreads();
    }

    if (isV) {
        const int n0v = n0 - 2 * DIM;
        #pragma unroll
        for (int i = 0; i < 4; i++) {
            const int base_m = m0 + wm + i * 16;
            const int b_idx = base_m >> 10;
            const int kvl = (base_m & 1023) + quad * 4;
            #pragma unroll
            for (int j = 0; j < 4; j++) {
                const int nl = n0v + wn + j * 16 + lq;
                const int h = nl >> 6;
                const int d = nl & 63;
                B4 pk;
                #pragma unroll
                for (int r = 0; r < 4; r++) pk.h[r] = (bf16)acc[i][j][r];
                *(s16x4*)&Vt[(((size_t)b_idx * NHEADS + h) * HDIM + d) * LKV + kvl] = pk.s;
            }
        }
    } else {
        bf16* Cb = (n0 < DIM) ? Qp : Kp;
        const int nb = (n0 < DIM) ? n0 : n0 - DIM;
        #pragma unroll
        for (int i = 0; i < 4; i++) {
            const size_t row = m0 + wm + i * 16 + lq;
            #pragma unroll
            for (int j = 0; j < 4; j++) {
                const int col = nb + wn + j * 16 + quad * 4;
                B4 pk;
                #pragma unroll
                for (int r = 0; r < 4; r++) pk.h[r] = (bf16)acc[i][j][r];
                *(s16x4*)&Cb[row * DIM + col] = pk.s;
            }
        }
    }
}

// ---------------- final GEMM: out[M,768] = Ob @ Wproj^T + bias (fp32) ----------------
__global__ __launch_bounds__(256) void out_gemm(
    const bf16* __restrict__ A, const bf16* __restrict__ B,
    float* __restrict__ Cp, const float* __restrict__ bias, int M, int N, int K)
{
    __shared__ bf16 As[128 * 40];
    __shared__ bf16 Bs[128 * 40];
    const int tid  = threadIdx.x;
    const int lane = tid & 63;
    const int w    = tid >> 6;
    const int wm = (w >> 1) * 64;
    const int wn = (w & 1) * 64;
    const int m0 = blockIdx.x * 128;
    const int n0 = blockIdx.y * 128;
    const int lq = lane & 15;
    const int quad = lane >> 4;
    const int row_l = tid >> 1;
    const int col_l = (tid & 1) * 16;

    f32x4 acc[4][4] = {};

    for (int k0 = 0; k0 < K; k0 += 32) {
        const bf16* ga = A + (size_t)(m0 + row_l) * K + k0 + col_l;
        const bf16* gb = B + (size_t)(n0 + row_l) * K + k0 + col_l;
        *(uint4*)&As[row_l * 40 + col_l]     = *(const uint4*)(ga);
        *(uint4*)&As[row_l * 40 + col_l + 8] = *(const uint4*)(ga + 8);
        *(uint4*)&Bs[row_l * 40 + col_l]     = *(const uint4*)(gb);
        *(uint4*)&Bs[row_l * 40 + col_l + 8] = *(const uint4*)(gb + 8);
        __syncthreads();

        bf16x8 a[4], b[4];
        #pragma unroll
        for (int i = 0; i < 4; i++)
            a[i] = *(const bf16x8*)&As[(wm + i * 16 + lq) * 40 + quad * 8];
        #pragma unroll
        for (int j = 0; j < 4; j++)
            b[j] = *(const bf16x8*)&Bs[(wn + j * 16 + lq) * 40 + quad * 8];
        #pragma unroll
        for (int i = 0; i < 4; i++)
            #pragma unroll
            for (int j = 0; j < 4; j++)
                acc[i][j] = mfma_k32(b[j], a[i], acc[i][j]);
        __syncthreads();
    }

    #pragma unroll
    for (int i = 0; i < 4; i++) {
        const size_t row = m0 + wm + i * 16 + lq;
        #pragma unroll
        for (int j = 0; j < 4; j++) {
            const int col = n0 + wn + j * 16 + quad * 4;
            float4 bj = *(const float4*)&bias[col];
            float4 o;
            o.x = acc[i][j][0] + bj.x; o.y = acc[i][j][1] + bj.y;
            o.z = acc[i][j][2] + bj.z; o.w = acc[i][j][3] + bj.w;
            *(float4*)&Cp[row * N + col] = o;
        }
    }
}

// ---------------- fused attention (transposed-S, 64-q blocks, Q direct-to-reg) ----------------
__global__ __launch_bounds__(256) void attn_kernel(
    const bf16* __restrict__ Qb,   // (B*LQ, 768)
    const bf16* __restrict__ Kb,   // (B*LKV, 768)
    const bf16* __restrict__ Vt,   // (B*H*64, LKV)
    const float* __restrict__ pos, // (H, LQ, LKV)
    bf16* __restrict__ O)          // (B*LQ, 768)
{
    __shared__ bf16 Ks[64 * 72];   // [kv][d]
    __shared__ bf16 Vs[64 * 72];   // [d][kv]

    const int by = blockIdx.y;     // h-major for pos L2 locality
    const int h = by >> 3, b = by & 7;
    const int bh = b * NHEADS + h;
    const int q0 = blockIdx.x * 64;
    const int t = threadIdx.x;
    const int lane = t & 63;
    const int w = t >> 6;
    const int lq = lane & 15;
    const int quad = lane >> 4;

    // Q fragments straight from global (aligned 16B each)
    const bf16* qg = Qb + (size_t)(b * LQ + q0 + w * 16 + lq) * DIM + h * HDIM + quad * 8;
    bf16x8 qa[2];
    qa[0] = *(const bf16x8*)(qg);
    qa[1] = *(const bf16x8*)(qg + 32);

    float m_r = -1e30f, l_r = 0.f;
    f32x4 o_acc[4] = {};

    const float4* pos4 = (const float4*)(pos + ((size_t)h * LQ + q0 + w * 16 + lq) * LKV);

    for (int kv0 = 0; kv0 < LKV; kv0 += 64) {
        #pragma unroll
        for (int p = 0; p < 2; p++) {
            int row = (t >> 3) + p * 32;
            int c8  = (t & 7) * 8;
            *(uint4*)&Ks[row * 72 + c8] =
                *(const uint4*)(Kb + (size_t)(b * LKV + kv0 + row) * DIM + h * HDIM + c8);
            *(uint4*)&Vs[row * 72 + c8] =
                *(const uint4*)(Vt + (size_t)(bh * HDIM + row) * LKV + kv0 + c8);
        }
        __syncthreads();

        float4 pb[4];
        #pragma unroll
        for (int kvblk = 0; kvblk < 4; kvblk++)
            pb[kvblk] = pos4[(kv0 >> 2) + kvblk * 4 + quad];

        f32x4 sc[4];
        #pragma unroll
        for (int kvblk = 0; kvblk < 4; kvblk++) {
            sc[kvblk] = (f32x4){0.f, 0.f, 0.f, 0.f};
            #pragma unroll
            for (int kt = 0; kt < 2; kt++) {
                bf16x8 ak = *(const bf16x8*)&Ks[(kvblk * 16 + lq) * 72 + kt * 32 + quad * 8];
                sc[kvblk] = mfma_k32(ak, qa[kt], sc[kvblk]);
            }
        }

        float sv[4][4];
        #pragma unroll
        for (int kvblk = 0; kvblk < 4; kvblk++) {
            sv[kvblk][0] = sc[kvblk][0] * ATTN_SCALE + pb[kvblk].x;
            sv[kvblk][1] = sc[kvblk][1] * ATTN_SCALE + pb[kvblk].y;
            sv[kvblk][2] = sc[kvblk][2] * ATTN_SCALE + pb[kvblk].z;
            sv[kvblk][3] = sc[kvblk][3] * ATTN_SCALE + pb[kvblk].w;
        }

        float tmax = sv[0][0];
        #pragma unroll
        for (int kvblk = 0; kvblk < 4; kvblk++)
            #pragma unroll
            for (int r = 0; r < 4; r++)
                tmax = fmaxf(tmax, sv[kvblk][r]);
        tmax = fmaxf(tmax, __shfl_xor(tmax, 16));
        tmax = fmaxf(tmax, __shfl_xor(tmax, 32));
        float mn = fmaxf(m_r, tmax);
        float alpha = __expf(m_r - mn);
        float rs = 0.f;
        B4 pfrag[4];
        #pragma unroll
        for (int kvblk = 0; kvblk < 4; kvblk++) {
            #pragma unroll
            for (int r = 0; r < 4; r++) {
                float pv = __expf(sv[kvblk][r] - mn);
                rs += pv;
                pfrag[kvblk].h[r] = (bf16)pv;
            }
        }
        rs += __shfl_xor(rs, 16);
        rs += __shfl_xor(rs, 32);
        l_r = l_r * alpha + rs;
        m_r = mn;

        #pragma unroll
        for (int dblk = 0; dblk < 4; dblk++) {
            o_acc[dblk][0] *= alpha; o_acc[dblk][1] *= alpha;
            o_acc[dblk][2] *= alpha; o_acc[dblk][3] *= alpha;
        }

        #pragma unroll
        for (int dblk = 0; dblk < 4; dblk++) {
            #pragma unroll
            for (int kvblk = 0; kvblk < 4; kvblk++) {
                s16x4 va = *(const s16x4*)&Vs[(dblk * 16 + lq) * 72 + kvblk * 16 + quad * 4];
                o_acc[dblk] = mfma_k16(va, pfrag[kvblk].s, o_acc[dblk]);
            }
        }
        __syncthreads();
    }

    float inv = 1.f / l_r;
    const size_t orow = (size_t)(b * LQ + q0 + w * 16 + lq) * DIM + h * HDIM;
    #pragma unroll
    for (int dblk = 0; dblk < 4; dblk++) {
        B4 ob;
        #pragma unroll
        for (int r = 0; r < 4; r++) ob.h[r] = (bf16)(o_acc[dblk][r] * inv);
        *(s16x4*)&O[orow + dblk * 16 + quad * 4] = ob.s;
    }
}

// ---------------- host ----------------
extern "C" void kernel_launch(void* const* d_in, const int* in_sizes, int n_in,
                              void* d_out, int out_size, void* d_ws, size_t ws_size,
                              hipStream_t stream) {
    const float* q     = (const float*)d_in[0];
    const float* kv    = (const float*)d_in[1];
    const float* pos   = (const float*)d_in[2];
    const float* Wq    = (const float*)d_in[3];
    const float* Wkv   = (const float*)d_in[4];
    const float* Wproj = (const float*)d_in[5];
    const float* bproj = (const float*)d_in[6];
    float* out = (float*)d_out;

    char* ws = (char*)d_ws;
    size_t off = 0;
    auto alloc = [&](size_t bytes) -> void* {
        void* p = ws + off;
        off += (bytes + 255) & ~(size_t)255;
        return p;
    };

    const int M = BATCH * LQ;   // 8192
    bf16* qb   = (bf16*)alloc((size_t)M * DIM * 2);
    bf16* kvb  = (bf16*)alloc((size_t)M * DIM * 2);
    bf16* wall = (bf16*)alloc((size_t)3 * DIM * DIM * 2);   // [Wq;Wkv] contiguous
    bf16* wpb  = (bf16*)alloc((size_t)DIM * DIM * 2);
    bf16* Qp   = (bf16*)alloc((size_t)M * DIM * 2);
    bf16* Kp   = (bf16*)alloc((size_t)M * DIM * 2);
    bf16* Vt   = (bf16*)alloc((size_t)BATCH * NHEADS * HDIM * LKV * 2);
    bf16* Ob   = (bf16*)alloc((size_t)M * DIM * 2);

    {
        int n4 = M * DIM / 4;
        cvt_qkv<<<dim3((n4 + 255) / 256, 2), 256, 0, stream>>>(
            (const float4*)q, (const float4*)kv, (bf16x4*)qb, (bf16x4*)kvb, n4);
        int w4 = DIM * DIM / 4;
        cvt_w<<<dim3((w4 + 255) / 256, 4), 256, 0, stream>>>(
            (const float4*)Wq, (const float4*)Wkv, (const float4*)Wproj,
            (bf16x4*)wall, (bf16x4*)wpb, w4);
    }

    // all three projections in one dispatch: N = 2304
    proj_gemm<<<dim3(M / 128, (3 * DIM) / 128), 256, 0, stream>>>(qb, kvb, wall, Qp, Kp, Vt);
    attn_kernel<<<dim3(LQ / 64, NHEADS * BATCH), 256, 0, stream>>>(Qp, Kp, Vt, pos, Ob);
    out_gemm<<<dim3(M / 128, DIM / 128), 256, 0, stream>>>(Ob, wpb, out, bproj, M, DIM, DIM);
}

// Round 6
// 299.463 us; speedup vs baseline: 1.1529x; 1.0585x over previous
//
#include <hip/hip_runtime.h>

#define DIM 768
#define NHEADS 12
#define HDIM 64
#define BATCH 8
#define LQ 1024
#define LKV 1024
#define ATTN_SCALE 0.125f

typedef __bf16 bf16;
typedef __bf16 bf16x4 __attribute__((ext_vector_type(4)));
typedef __bf16 bf16x8 __attribute__((ext_vector_type(8)));
typedef short s16x4 __attribute__((ext_vector_type(4)));
typedef float f32x4 __attribute__((ext_vector_type(4)));

union B4 { bf16x4 h; s16x4 s; };

static __device__ __forceinline__ f32x4 mfma_k32(bf16x8 a, bf16x8 b, f32x4 c) {
    return __builtin_amdgcn_mfma_f32_16x16x32_bf16(a, b, c, 0, 0, 0);
}
static __device__ __forceinline__ f32x4 mfma_k16(s16x4 a, s16x4 b, f32x4 c) {
    return __builtin_amdgcn_mfma_f32_16x16x16bf16_1k(a, b, c, 0, 0, 0);
}

// async global->LDS: one instruction per wave; lane i's 16B lands at lds + i*16B.
static __device__ __forceinline__ void async16(const bf16* g, bf16* l) {
    __builtin_amdgcn_global_load_lds(
        (const __attribute__((address_space(1))) unsigned int*)g,
        (__attribute__((address_space(3))) unsigned int*)l, 16, 0, 0);
}
// Explicit drain of the async queue BEFORE the barrier. Round-3 evidence:
// without this, graph replays race (compiler does not order the builtin's
// LDS side-effect against s_barrier). "memory" clobber also stops reordering.
static __device__ __forceinline__ void drain_vmem() {
    __asm__ volatile("s_waitcnt vmcnt(0)" ::: "memory");
}

// ---------------- fp32 -> bf16 converts (fused multi-tensor) ----------------
__global__ void cvt_qkv(const float4* __restrict__ q, const float4* __restrict__ kv,
                        bf16x4* __restrict__ qb, bf16x4* __restrict__ kvb, int n4) {
    int i = blockIdx.x * 256 + threadIdx.x;
    if (i >= n4) return;
    const float4* src = blockIdx.y ? kv : q;
    bf16x4* dst = blockIdx.y ? kvb : qb;
    float4 v = src[i];
    bf16x4 o;
    o[0] = (bf16)v.x; o[1] = (bf16)v.y; o[2] = (bf16)v.z; o[3] = (bf16)v.w;
    dst[i] = o;
}

__global__ void cvt_w(const float4* __restrict__ Wq, const float4* __restrict__ Wkv,
                      const float4* __restrict__ Wp,
                      bf16x4* __restrict__ wall, bf16x4* __restrict__ wpb, int n4) {
    int i = blockIdx.x * 256 + threadIdx.x;
    if (i >= n4) return;
    int y = blockIdx.y;
    const float4* src; bf16x4* dst;
    if (y == 0)      { src = Wq;             dst = wall; }
    else if (y == 3) { src = Wp;             dst = wpb; }
    else             { src = Wkv + (y - 1) * n4; dst = wall + y * n4; }
    float4 v = src[i];
    bf16x4 o;
    o[0] = (bf16)v.x; o[1] = (bf16)v.y; o[2] = (bf16)v.z; o[3] = (bf16)v.w;
    dst[i] = o;
}

// ---------------- fused projection GEMM (async staging, m97 structure) ----------------
// C[8192, 2304] = [qb|kvb] @ [Wq;WkvK;WkvV]^T, column range picks A + epilogue:
//   n0 in [0,768):     Qp bf16 (swapped epilogue)
//   n0 in [768,1536):  Kp bf16 (swapped)
//   n0 in [1536,2304): Vt (B,H,64,LKV) transposed (non-swapped)
__global__ __launch_bounds__(256) void proj_gemm(
    const bf16* __restrict__ qb, const bf16* __restrict__ kvb,
    const bf16* __restrict__ W,   // 2304 x 768 bf16
    bf16* __restrict__ Qp, bf16* __restrict__ Kp, bf16* __restrict__ Vt)
{
    __shared__ bf16 As[128 * 32];
    __shared__ bf16 Bs[128 * 32];
    const int tid  = threadIdx.x;
    const int lane = tid & 63;
    const int w    = tid >> 6;
    const int wm = (w >> 1) * 64;
    const int wn = (w & 1) * 64;
    const int m0 = blockIdx.x * 128;
    const int n0 = blockIdx.y * 128;
    const int K = DIM;
    const int lq = lane & 15;
    const int quad = lane >> 4;

    const bf16* A = (n0 < DIM) ? qb : kvb;
    const int isV = (n0 >= 2 * DIM);

    // staging: wave w covers tile rows [w*32, w*32+32), 2 issues of 16 rows each
    const int rl = lane >> 2;          // 0..15
    const int ck = (lane & 3) * 8;     // 0,8,16,24
    const bf16* gA = A + (size_t)(m0 + w * 32 + rl) * K + ck;
    const bf16* gB = W + (size_t)(n0 + w * 32 + rl) * K + ck;
    bf16* lA = &As[w * 1024];
    bf16* lB = &Bs[w * 1024];

    f32x4 acc[4][4] = {};

    for (int k0 = 0; k0 < K; k0 += 32) {
        async16(gA + k0,                  lA);
        async16(gA + (size_t)16 * K + k0, lA + 512);
        async16(gB + k0,                  lB);
        async16(gB + (size_t)16 * K + k0, lB + 512);
        drain_vmem();
        __syncthreads();

        bf16x8 a[4], b[4];
        #pragma unroll
        for (int i = 0; i < 4; i++)
            a[i] = *(const bf16x8*)&As[(wm + i * 16 + lq) * 32 + quad * 8];
        #pragma unroll
        for (int j = 0; j < 4; j++)
            b[j] = *(const bf16x8*)&Bs[(wn + j * 16 + lq) * 32 + quad * 8];
        if (isV) {
            #pragma unroll
            for (int i = 0; i < 4; i++)
                #pragma unroll
                for (int j = 0; j < 4; j++)
                    acc[i][j] = mfma_k32(a[i], b[j], acc[i][j]);
        } else {
            #pragma unroll
            for (int i = 0; i < 4; i++)
                #pragma unroll
                for (int j = 0; j < 4; j++)
                    acc[i][j] = mfma_k32(b[j], a[i], acc[i][j]);
        }
        __syncthreads();
    }

    if (isV) {
        const int n0v = n0 - 2 * DIM;
        #pragma unroll
        for (int i = 0; i < 4; i++) {
            const int base_m = m0 + wm + i * 16;
            const int b_idx = base_m >> 10;
            const int kvl = (base_m & 1023) + quad * 4;
            #pragma unroll
            for (int j = 0; j < 4; j++) {
                const int nl = n0v + wn + j * 16 + lq;
                const int h = nl >> 6;
                const int d = nl & 63;
                B4 pk;
                #pragma unroll
                for (int r = 0; r < 4; r++) pk.h[r] = (bf16)acc[i][j][r];
                *(s16x4*)&Vt[(((size_t)b_idx * NHEADS + h) * HDIM + d) * LKV + kvl] = pk.s;
            }
        }
    } else {
        bf16* Cb = (n0 < DIM) ? Qp : Kp;
        const int nb = (n0 < DIM) ? n0 : n0 - DIM;
        #pragma unroll
        for (int i = 0; i < 4; i++) {
            const size_t row = m0 + wm + i * 16 + lq;
            #pragma unroll
            for (int j = 0; j < 4; j++) {
                const int col = nb + wn + j * 16 + quad * 4;
                B4 pk;
                #pragma unroll
                for (int r = 0; r < 4; r++) pk.h[r] = (bf16)acc[i][j][r];
                *(s16x4*)&Cb[row * DIM + col] = pk.s;
            }
        }
    }
}

// ---------------- final GEMM: out[M,768] = Ob @ Wproj^T + bias (fp32, async staging) ----------------
__global__ __launch_bounds__(256) void out_gemm(
    const bf16* __restrict__ A, const bf16* __restrict__ B,
    float* __restrict__ Cp, const float* __restrict__ bias, int M, int N, int K)
{
    __shared__ bf16 As[128 * 32];
    __shared__ bf16 Bs[128 * 32];
    const int tid  = threadIdx.x;
    const int lane = tid & 63;
    const int w    = tid >> 6;
    const int wm = (w >> 1) * 64;
    const int wn = (w & 1) * 64;
    const int m0 = blockIdx.x * 128;
    const int n0 = blockIdx.y * 128;
    const int lq = lane & 15;
    const int quad = lane >> 4;

    const int rl = lane >> 2;
    const int ck = (lane & 3) * 8;
    const bf16* gA = A + (size_t)(m0 + w * 32 + rl) * K + ck;
    const bf16* gB = B + (size_t)(n0 + w * 32 + rl) * K + ck;
    bf16* lA = &As[w * 1024];
    bf16* lB = &Bs[w * 1024];

    f32x4 acc[4][4] = {};

    for (int k0 = 0; k0 < K; k0 += 32) {
        async16(gA + k0,                  lA);
        async16(gA + (size_t)16 * K + k0, lA + 512);
        async16(gB + k0,                  lB);
        async16(gB + (size_t)16 * K + k0, lB + 512);
        drain_vmem();
        __syncthreads();

        bf16x8 a[4], b[4];
        #pragma unroll
        for (int i = 0; i < 4; i++)
            a[i] = *(const bf16x8*)&As[(wm + i * 16 + lq) * 32 + quad * 8];
        #pragma unroll
        for (int j = 0; j < 4; j++)
            b[j] = *(const bf16x8*)&Bs[(wn + j * 16 + lq) * 32 + quad * 8];
        #pragma unroll
        for (int i = 0; i < 4; i++)
            #pragma unroll
            for (int j = 0; j < 4; j++)
                acc[i][j] = mfma_k32(b[j], a[i], acc[i][j]);
        __syncthreads();
    }

    #pragma unroll
    for (int i = 0; i < 4; i++) {
        const size_t row = m0 + wm + i * 16 + lq;
        #pragma unroll
        for (int j = 0; j < 4; j++) {
            const int col = n0 + wn + j * 16 + quad * 4;
            float4 bj = *(const float4*)&bias[col];
            float4 o;
            o.x = acc[i][j][0] + bj.x; o.y = acc[i][j][1] + bj.y;
            o.z = acc[i][j][2] + bj.z; o.w = acc[i][j][3] + bj.w;
            *(float4*)&Cp[row * N + col] = o;
        }
    }
}

// ---------------- fused attention (transposed-S, 64-q blocks, Q direct-to-reg) ----------------
__global__ __launch_bounds__(256) void attn_kernel(
    const bf16* __restrict__ Qb,   // (B*LQ, 768)
    const bf16* __restrict__ Kb,   // (B*LKV, 768)
    const bf16* __restrict__ Vt,   // (B*H*64, LKV)
    const float* __restrict__ pos, // (H, LQ, LKV)
    bf16* __restrict__ O)          // (B*LQ, 768)
{
    __shared__ bf16 Ks[64 * 72];   // [kv][d]
    __shared__ bf16 Vs[64 * 72];   // [d][kv]

    const int by = blockIdx.y;     // h-major for pos L2 locality
    const int h = by >> 3, b = by & 7;
    const int bh = b * NHEADS + h;
    const int q0 = blockIdx.x * 64;
    const int t = threadIdx.x;
    const int lane = t & 63;
    const int w = t >> 6;
    const int lq = lane & 15;
    const int quad = lane >> 4;

    const bf16* qg = Qb + (size_t)(b * LQ + q0 + w * 16 + lq) * DIM + h * HDIM + quad * 8;
    bf16x8 qa[2];
    qa[0] = *(const bf16x8*)(qg);
    qa[1] = *(const bf16x8*)(qg + 32);

    float m_r = -1e30f, l_r = 0.f;
    f32x4 o_acc[4] = {};

    const float4* pos4 = (const float4*)(pos + ((size_t)h * LQ + q0 + w * 16 + lq) * LKV);

    for (int kv0 = 0; kv0 < LKV; kv0 += 64) {
        #pragma unroll
        for (int p = 0; p < 2; p++) {
            int row = (t >> 3) + p * 32;
            int c8  = (t & 7) * 8;
            *(uint4*)&Ks[row * 72 + c8] =
                *(const uint4*)(Kb + (size_t)(b * LKV + kv0 + row) * DIM + h * HDIM + c8);
            *(uint4*)&Vs[row * 72 + c8] =
                *(const uint4*)(Vt + (size_t)(bh * HDIM + row) * LKV + kv0 + c8);
        }
        __syncthreads();

        float4 pb[4];
        #pragma unroll
        for (int kvblk = 0; kvblk < 4; kvblk++)
            pb[kvblk] = pos4[(kv0 >> 2) + kvblk * 4 + quad];

        f32x4 sc[4];
        #pragma unroll
        for (int kvblk = 0; kvblk < 4; kvblk++) {
            sc[kvblk] = (f32x4){0.f, 0.f, 0.f, 0.f};
            #pragma unroll
            for (int kt = 0; kt < 2; kt++) {
                bf16x8 ak = *(const bf16x8*)&Ks[(kvblk * 16 + lq) * 72 + kt * 32 + quad * 8];
                sc[kvblk] = mfma_k32(ak, qa[kt], sc[kvblk]);
            }
        }

        float sv[4][4];
        #pragma unroll
        for (int kvblk = 0; kvblk < 4; kvblk++) {
            sv[kvblk][0] = sc[kvblk][0] * ATTN_SCALE + pb[kvblk].x;
            sv[kvblk][1] = sc[kvblk][1] * ATTN_SCALE + pb[kvblk].y;
            sv[kvblk][2] = sc[kvblk][2] * ATTN_SCALE + pb[kvblk].z;
            sv[kvblk][3] = sc[kvblk][3] * ATTN_SCALE + pb[kvblk].w;
        }

        float tmax = sv[0][0];
        #pragma unroll
        for (int kvblk = 0; kvblk < 4; kvblk++)
            #pragma unroll
            for (int r = 0; r < 4; r++)
                tmax = fmaxf(tmax, sv[kvblk][r]);
        tmax = fmaxf(tmax, __shfl_xor(tmax, 16));
        tmax = fmaxf(tmax, __shfl_xor(tmax, 32));
        float mn = fmaxf(m_r, tmax);
        float alpha = __expf(m_r - mn);
        float rs = 0.f;
        B4 pfrag[4];
        #pragma unroll
        for (int kvblk = 0; kvblk < 4; kvblk++) {
            #pragma unroll
            for (int r = 0; r < 4; r++) {
                float pv = __expf(sv[kvblk][r] - mn);
                rs += pv;
                pfrag[kvblk].h[r] = (bf16)pv;
            }
        }
        rs += __shfl_xor(rs, 16);
        rs += __shfl_xor(rs, 32);
        l_r = l_r * alpha + rs;
        m_r = mn;

        #pragma unroll
        for (int dblk = 0; dblk < 4; dblk++) {
            o_acc[dblk][0] *= alpha; o_acc[dblk][1] *= alpha;
            o_acc[dblk][2] *= alpha; o_acc[dblk][3] *= alpha;
        }

        #pragma unroll
        for (int dblk = 0; dblk < 4; dblk++) {
            #pragma unroll
            for (int kvblk = 0; kvblk < 4; kvblk++) {
                s16x4 va = *(const s16x4*)&Vs[(dblk * 16 + lq) * 72 + kvblk * 16 + quad * 4];
                o_acc[dblk] = mfma_k16(va, pfrag[kvblk].s, o_acc[dblk]);
            }
        }
        __syncthreads();
    }

    float inv = 1.f / l_r;
    const size_t orow = (size_t)(b * LQ + q0 + w * 16 + lq) * DIM + h * HDIM;
    #pragma unroll
    for (int dblk = 0; dblk < 4; dblk++) {
        B4 ob;
        #pragma unroll
        for (int r = 0; r < 4; r++) ob.h[r] = (bf16)(o_acc[dblk][r] * inv);
        *(s16x4*)&O[orow + dblk * 16 + quad * 4] = ob.s;
    }
}

// ---------------- host ----------------
extern "C" void kernel_launch(void* const* d_in, const int* in_sizes, int n_in,
                              void* d_out, int out_size, void* d_ws, size_t ws_size,
                              hipStream_t stream) {
    const float* q     = (const float*)d_in[0];
    const float* kv    = (const float*)d_in[1];
    const float* pos   = (const float*)d_in[2];
    const float* Wq    = (const float*)d_in[3];
    const float* Wkv   = (const float*)d_in[4];
    const float* Wproj = (const float*)d_in[5];
    const float* bproj = (const float*)d_in[6];
    float* out = (float*)d_out;

    char* ws = (char*)d_ws;
    size_t off = 0;
    auto alloc = [&](size_t bytes) -> void* {
        void* p = ws + off;
        off += (bytes + 255) & ~(size_t)255;
        return p;
    };

    const int M = BATCH * LQ;   // 8192
    bf16* qb   = (bf16*)alloc((size_t)M * DIM * 2);
    bf16* kvb  = (bf16*)alloc((size_t)M * DIM * 2);
    bf16* wall = (bf16*)alloc((size_t)3 * DIM * DIM * 2);
    bf16* wpb  = (bf16*)alloc((size_t)DIM * DIM * 2);
    bf16* Qp   = (bf16*)alloc((size_t)M * DIM * 2);
    bf16* Kp   = (bf16*)alloc((size_t)M * DIM * 2);
    bf16* Vt   = (bf16*)alloc((size_t)BATCH * NHEADS * HDIM * LKV * 2);
    bf16* Ob   = (bf16*)alloc((size_t)M * DIM * 2);

    {
        int n4 = M * DIM / 4;
        cvt_qkv<<<dim3((n4 + 255) / 256, 2), 256, 0, stream>>>(
            (const float4*)q, (const float4*)kv, (bf16x4*)qb, (bf16x4*)kvb, n4);
        int w4 = DIM * DIM / 4;
        cvt_w<<<dim3((w4 + 255) / 256, 4), 256, 0, stream>>>(
            (const float4*)Wq, (const float4*)Wkv, (const float4*)Wproj,
            (bf16x4*)wall, (bf16x4*)wpb, w4);
    }

    proj_gemm<<<dim3(M / 128, (3 * DIM) / 128), 256, 0, stream>>>(qb, kvb, wall, Qp, Kp, Vt);
    attn_kernel<<<dim3(LQ / 64, NHEADS * BATCH), 256, 0, stream>>>(Qp, Kp, Vt, pos, Ob);
    out_gemm<<<dim3(M / 128, DIM / 128), 256, 0, stream>>>(Ob, wpb, out, bproj, M, DIM, DIM);
}